// Round 5
// baseline (253.601 us; speedup 1.0000x reference)
//
#include <hip/hip_runtime.h>

// SoftPhongNormalShader, two-phase:
//   Phase 1: per-face 16-B row: 3 vertex normals as 3x10-bit unorm codes per
//            dword. 1.6 MB, L2-resident; ONE divergent 16-B load/fragment.
//   Phase 2: per-pixel shade + softmax blend, TWO pixels per thread to double
//            per-wave MLP (~42 outstanding loads) — R4 showed all pipes idle
//            (HBM 17%, VALU 16%, occ 42%): latency-bound, not rate-bound.

typedef float        f4 __attribute__((ext_vector_type(4)));
typedef int          i4 __attribute__((ext_vector_type(4)));
typedef unsigned int u32;
typedef u32          u4 __attribute__((ext_vector_type(4)));

#define KFRAG 8
#define PPT 2                  // pixels per thread
#define SIGMA_INV 10000.0f     // 1/1e-4
#define GAMMA_INV 10000.0f     // 1/1e-4
#define ZFAR 100.0f
#define ZRANGE_INV (1.0f / 99.0f)
#define EPSV 1e-10f
#define QSCALE 1023.0f
#define QINV (1.0f / 1023.0f)

__device__ __forceinline__ u32 pack10(float x, float y, float z) {
    // map [-1,1] -> [0,1023] unorm; code/1023 == (n+1)/2
    u32 qx = (u32)__float2int_rn(__saturatef(x * 0.5f + 0.5f) * QSCALE);
    u32 qy = (u32)__float2int_rn(__saturatef(y * 0.5f + 0.5f) * QSCALE);
    u32 qz = (u32)__float2int_rn(__saturatef(z * 0.5f + 0.5f) * QSCALE);
    return qx | (qy << 10) | (qz << 20);
}

__global__ __launch_bounds__(256) void build_face_tab(
    const float* __restrict__ vn,     // [V,3]
    const int*   __restrict__ faces,  // [F,3]
    u4*          __restrict__ tab,    // [F] 16-B rows
    int F)
{
    int f = blockIdx.x * blockDim.x + threadIdx.x;
    if (f >= F) return;
    int v0 = faces[3*f + 0];
    int v1 = faces[3*f + 1];
    int v2 = faces[3*f + 2];
    u4 row;
    row.x = pack10(vn[3*v0], vn[3*v0+1], vn[3*v0+2]);
    row.y = pack10(vn[3*v1], vn[3*v1+1], vn[3*v1+2]);
    row.z = pack10(vn[3*v2], vn[3*v2+1], vn[3*v2+2]);
    row.w = 0;
    tab[f] = row;
}

__global__ __launch_bounds__(256) void soft_phong_kernel(
    const u4*    __restrict__ tab,    // [F] packed face rows
    const float* __restrict__ bary,   // [P,K,3]
    const float* __restrict__ zbuf,   // [P,K]
    const float* __restrict__ dists,  // [P,K]
    const int*   __restrict__ p2f,    // [P,K]
    float*       __restrict__ out,    // [P,4]
    int P)
{
    // two coalesced pixels per thread: p and p + 256
    int base = blockIdx.x * (256 * PPT) + threadIdx.x;

    int   fk[PPT * KFRAG];
    u4    ga[PPT * KFRAG];
    float zk[PPT * KFRAG], dk[PPT * KFRAG];
    float bf[PPT * KFRAG * 3];

    // ---- issue ALL loads for both pixels up front (max MLP) ----
    #pragma unroll
    for (int q = 0; q < PPT; q++) {
        int p = base + q * 256;
        if (p >= P) continue;
        const i4* pf4 = (const i4*)(p2f + (size_t)p * KFRAG);
        i4 fa = pf4[0], fb = pf4[1];
        fk[q*8+0]=fa.x; fk[q*8+1]=fa.y; fk[q*8+2]=fa.z; fk[q*8+3]=fa.w;
        fk[q*8+4]=fb.x; fk[q*8+5]=fb.y; fk[q*8+6]=fb.z; fk[q*8+7]=fb.w;
    }
    #pragma unroll
    for (int j = 0; j < PPT * KFRAG; j++) {
        int fi = fk[j] >= 0 ? fk[j] : 0;
        ga[j] = tab[fi];                       // 16 divergent loads in flight
    }
    #pragma unroll
    for (int q = 0; q < PPT; q++) {
        int p = base + q * 256;
        if (p >= P) continue;
        const f4* z4 = (const f4*)(zbuf + (size_t)p * KFRAG);
        f4 za = z4[0], zb = z4[1];
        zk[q*8+0]=za.x; zk[q*8+1]=za.y; zk[q*8+2]=za.z; zk[q*8+3]=za.w;
        zk[q*8+4]=zb.x; zk[q*8+5]=zb.y; zk[q*8+6]=zb.z; zk[q*8+7]=zb.w;
        const f4* dd4 = (const f4*)(dists + (size_t)p * KFRAG);
        f4 da = dd4[0], db = dd4[1];
        dk[q*8+0]=da.x; dk[q*8+1]=da.y; dk[q*8+2]=da.z; dk[q*8+3]=da.w;
        dk[q*8+4]=db.x; dk[q*8+5]=db.y; dk[q*8+6]=db.z; dk[q*8+7]=db.w;
        const f4* b4 = (const f4*)(bary + (size_t)p * KFRAG * 3);
        #pragma unroll
        for (int j = 0; j < 6; j++) {
            f4 t = b4[j];
            bf[q*24+4*j+0]=t.x; bf[q*24+4*j+1]=t.y;
            bf[q*24+4*j+2]=t.z; bf[q*24+4*j+3]=t.w;
        }
    }

    // ---- per-pixel shading + softmax blend ----
    #pragma unroll
    for (int q = 0; q < PPT; q++) {
        int p = base + q * 256;
        if (p >= P) continue;

        float prob[KFRAG], zinv[KFRAG];
        float cr[KFRAG], cg[KFRAG], cb[KFRAG];
        float zmax = EPSV;

        #pragma unroll
        for (int k = 0; k < KFRAG; k++) {
            int j = q * KFRAG + k;
            bool m = (fk[j] >= 0);
            float b0 = bf[q*24 + 3*k + 0];
            float b1 = bf[q*24 + 3*k + 1];
            float b2 = bf[q*24 + 3*k + 2];
            u32 w0 = ga[j].x, w1 = ga[j].y, w2 = ga[j].z;
            // code/1023 = (n+1)/2; sum(b)=1 so colors interpolate directly
            float sx = b0*(float)(w0 & 1023u) + b1*(float)(w1 & 1023u)
                     + b2*(float)(w2 & 1023u);
            float sy = b0*(float)((w0 >> 10) & 1023u)
                     + b1*(float)((w1 >> 10) & 1023u)
                     + b2*(float)((w2 >> 10) & 1023u);
            float sz = b0*(float)(w0 >> 20) + b1*(float)(w1 >> 20)
                     + b2*(float)(w2 >> 20);
            cr[k] = sx * QINV;
            cg[k] = 1.0f - sy * QINV;
            cb[k] = 1.0f - sz * QINV;

            prob[k] = m ? (1.0f / (1.0f + __expf(dk[j] * SIGMA_INV))) : 0.0f;
            zinv[k] = m ? ((ZFAR - zk[j]) * ZRANGE_INV) : 0.0f;
            zmax = fmaxf(zmax, zinv[k]);
        }

        float delta = fmaxf(__expf((EPSV - zmax) * GAMMA_INV), EPSV);
        float denom = delta;
        float wr = 0.0f, wg = 0.0f, wb = 0.0f;
        float trans = 1.0f;

        #pragma unroll
        for (int k = 0; k < KFRAG; k++) {
            float w = prob[k] * __expf((zinv[k] - zmax) * GAMMA_INV);
            denom += w;
            wr += w * cr[k];
            wg += w * cg[k];
            wb += w * cb[k];
            trans *= (1.0f - prob[k]);
        }

        float inv = 1.0f / denom;
        f4 o = {(wr + delta) * inv, (wg + delta) * inv,
                (wb + delta) * inv, trans};
        __builtin_nontemporal_store(o, (f4*)out + p);
    }
}

extern "C" void kernel_launch(void* const* d_in, const int* in_sizes, int n_in,
                              void* d_out, int out_size, void* d_ws, size_t ws_size,
                              hipStream_t stream) {
    const float* vn    = (const float*)d_in[0];  // verts_normals [V,3]
    const float* bary  = (const float*)d_in[1];  // [N,H,W,K,3]
    const float* zbuf  = (const float*)d_in[2];  // [N,H,W,K]
    const float* dists = (const float*)d_in[3];  // [N,H,W,K]
    const int*   faces = (const int*)d_in[4];    // [F,3]
    const int*   p2f   = (const int*)d_in[5];    // [N,H,W,K]
    float* out = (float*)d_out;                  // [N,H,W,4]

    int P = in_sizes[2] / KFRAG;   // N*H*W
    int F = in_sizes[4] / 3;

    u4* tab = (u4*)d_ws;           // F * 16 B = 1.6 MB
    int block = 256;
    build_face_tab<<<(F + block - 1) / block, block, 0, stream>>>(
        vn, faces, tab, F);
    int grid = (P + block * PPT - 1) / (block * PPT);
    soft_phong_kernel<<<grid, block, 0, stream>>>(
        tab, bary, zbuf, dists, p2f, out, P);
}

// Round 6
// 242.481 us; speedup vs baseline: 1.0459x; 1.0459x over previous
//
#include <hip/hip_runtime.h>

// SoftPhongNormalShader, two-phase (best config, R4):
//   Phase 1: per-face table, ONE 16-B row per face: 3 vertex normals packed
//            as 3x10-bit unorm codes per dword ({n0,n1,n2,0}). 1.6 MB ->
//            L2-resident; exactly ONE divergent 16-B load per fragment.
//   Phase 2: per-pixel shade + softmax blend. Colors are affine in n and
//            sum(bary)=1, so we interpolate the unorm codes directly.
//
// Measured model (R1-R5): per-CU divergent line-processing at ~4.6 cyc/line;
// (8 gather + 3.5 stream + 1 store) lines/pixel -> ~88 us structural floor.
// PPT=2 (R5) regressed: request pipe saturates at ~19% occupancy already.

typedef float        f4 __attribute__((ext_vector_type(4)));
typedef int          i4 __attribute__((ext_vector_type(4)));
typedef unsigned int u32;
typedef u32          u4 __attribute__((ext_vector_type(4)));

#define KFRAG 8
#define SIGMA_INV 10000.0f     // 1/1e-4
#define GAMMA_INV 10000.0f     // 1/1e-4
#define ZFAR 100.0f
#define ZRANGE_INV (1.0f / 99.0f)
#define EPSV 1e-10f
#define QSCALE 1023.0f
#define QINV (1.0f / 1023.0f)

__device__ __forceinline__ u32 pack10(float x, float y, float z) {
    // map [-1,1] -> [0,1023] unorm code; code/1023 == (n+1)/2
    u32 qx = (u32)__float2int_rn(__saturatef(x * 0.5f + 0.5f) * QSCALE);
    u32 qy = (u32)__float2int_rn(__saturatef(y * 0.5f + 0.5f) * QSCALE);
    u32 qz = (u32)__float2int_rn(__saturatef(z * 0.5f + 0.5f) * QSCALE);
    return qx | (qy << 10) | (qz << 20);
}

__global__ __launch_bounds__(256) void build_face_tab(
    const float* __restrict__ vn,     // [V,3]
    const int*   __restrict__ faces,  // [F,3]
    u4*          __restrict__ tab,    // [F] 16-B rows
    int F)
{
    int f = blockIdx.x * blockDim.x + threadIdx.x;
    if (f >= F) return;
    int v0 = faces[3*f + 0];
    int v1 = faces[3*f + 1];
    int v2 = faces[3*f + 2];
    u4 row;
    row.x = pack10(vn[3*v0], vn[3*v0+1], vn[3*v0+2]);
    row.y = pack10(vn[3*v1], vn[3*v1+1], vn[3*v1+2]);
    row.z = pack10(vn[3*v2], vn[3*v2+1], vn[3*v2+2]);
    row.w = 0;
    tab[f] = row;
}

__global__ __launch_bounds__(256) void soft_phong_kernel(
    const u4*    __restrict__ tab,    // [F] packed face rows
    const float* __restrict__ bary,   // [P,K,3]
    const float* __restrict__ zbuf,   // [P,K]
    const float* __restrict__ dists,  // [P,K]
    const int*   __restrict__ p2f,    // [P,K]
    float*       __restrict__ out,    // [P,4]
    int P)
{
    int p = blockIdx.x * blockDim.x + threadIdx.x;
    if (p >= P) return;

    // ---- streaming loads (contiguous; L2/L3-resident across replays) ----
    const i4* pf4 = (const i4*)(p2f + (size_t)p * KFRAG);
    i4 fa = pf4[0], fb = pf4[1];
    int fk[KFRAG] = {fa.x, fa.y, fa.z, fa.w, fb.x, fb.y, fb.z, fb.w};

    const f4* z4 = (const f4*)(zbuf + (size_t)p * KFRAG);
    f4 za = z4[0], zb = z4[1];
    float zk[KFRAG] = {za.x, za.y, za.z, za.w, zb.x, zb.y, zb.z, zb.w};

    const f4* dd4 = (const f4*)(dists + (size_t)p * KFRAG);
    f4 da = dd4[0], db = dd4[1];
    float dk[KFRAG] = {da.x, da.y, da.z, da.w, db.x, db.y, db.z, db.w};

    const f4* b4 = (const f4*)(bary + (size_t)p * KFRAG * 3);
    float bf[24];
    #pragma unroll
    for (int j = 0; j < 6; j++) {
        f4 t = b4[j];
        bf[4*j+0] = t.x; bf[4*j+1] = t.y; bf[4*j+2] = t.z; bf[4*j+3] = t.w;
    }

    // ---- face-table gathers: exactly one 16-B load per fragment ----
    u4 ga[KFRAG];
    #pragma unroll
    for (int k = 0; k < KFRAG; k++) {
        int fi = fk[k] >= 0 ? fk[k] : 0;
        ga[k] = tab[fi];
    }

    // ---- per-fragment shading + blend precompute ----
    float prob[KFRAG], zinv[KFRAG];
    float cr[KFRAG], cg[KFRAG], cb[KFRAG];
    float zmax = EPSV;

    #pragma unroll
    for (int k = 0; k < KFRAG; k++) {
        bool m = (fk[k] >= 0);
        float b0 = bf[3*k + 0], b1 = bf[3*k + 1], b2 = bf[3*k + 2];

        u32 w0 = ga[k].x, w1 = ga[k].y, w2 = ga[k].z;
        // code/1023 = (n+1)/2; since b0+b1+b2 = 1:
        //   cr = (nx+1)/2 = (Σ b q_x)/1023 ; cg,cb = 1 - (Σ b q_{y,z})/1023
        float sx = b0 * (float)(w0 & 1023u)
                 + b1 * (float)(w1 & 1023u)
                 + b2 * (float)(w2 & 1023u);
        float sy = b0 * (float)((w0 >> 10) & 1023u)
                 + b1 * (float)((w1 >> 10) & 1023u)
                 + b2 * (float)((w2 >> 10) & 1023u);
        float sz = b0 * (float)(w0 >> 20)
                 + b1 * (float)(w1 >> 20)
                 + b2 * (float)(w2 >> 20);
        cr[k] = sx * QINV;
        cg[k] = 1.0f - sy * QINV;
        cb[k] = 1.0f - sz * QINV;

        prob[k] = m ? (1.0f / (1.0f + __expf(dk[k] * SIGMA_INV))) : 0.0f;
        zinv[k] = m ? ((ZFAR - zk[k]) * ZRANGE_INV) : 0.0f;
        zmax = fmaxf(zmax, zinv[k]);
    }

    // ---- softmax blend ----
    float delta = fmaxf(__expf((EPSV - zmax) * GAMMA_INV), EPSV);
    float denom = delta;
    float wr = 0.0f, wg = 0.0f, wb = 0.0f;
    float trans = 1.0f;

    #pragma unroll
    for (int k = 0; k < KFRAG; k++) {
        float w = prob[k] * __expf((zinv[k] - zmax) * GAMMA_INV);
        denom += w;
        wr += w * cr[k];
        wg += w * cg[k];
        wb += w * cb[k];
        trans *= (1.0f - prob[k]);
    }

    float inv = 1.0f / denom;
    f4 o = {(wr + delta) * inv, (wg + delta) * inv, (wb + delta) * inv, trans};
    __builtin_nontemporal_store(o, (f4*)out + p);   // write-once, keep out of caches
}

extern "C" void kernel_launch(void* const* d_in, const int* in_sizes, int n_in,
                              void* d_out, int out_size, void* d_ws, size_t ws_size,
                              hipStream_t stream) {
    const float* vn    = (const float*)d_in[0];  // verts_normals [V,3]
    const float* bary  = (const float*)d_in[1];  // [N,H,W,K,3]
    const float* zbuf  = (const float*)d_in[2];  // [N,H,W,K]
    const float* dists = (const float*)d_in[3];  // [N,H,W,K]
    const int*   faces = (const int*)d_in[4];    // [F,3]
    const int*   p2f   = (const int*)d_in[5];    // [N,H,W,K]
    float* out = (float*)d_out;                  // [N,H,W,4]

    int P = in_sizes[2] / KFRAG;   // N*H*W
    int F = in_sizes[4] / 3;

    u4* tab = (u4*)d_ws;           // F * 16 B = 1.6 MB
    int block = 256;
    build_face_tab<<<(F + block - 1) / block, block, 0, stream>>>(
        vn, faces, tab, F);
    soft_phong_kernel<<<(P + block - 1) / block, block, 0, stream>>>(
        tab, bary, zbuf, dists, p2f, out, P);
}